// Round 3
// baseline (894.242 us; speedup 1.0000x reference)
//
#include <hip/hip_runtime.h>
#include <math.h>

// Problem constants
#define NL 2
#define NDIR 4
#define DD 256     // D (channels)
#define DIN 512    // DI (inner)
#define NS 16      // N (state)
#define BB 8       // batch
#define LL 256     // L = H*W
#define BL 2048    // B*L

typedef short s16x8 __attribute__((ext_vector_type(8)));
typedef short s16x4 __attribute__((ext_vector_type(4)));
typedef float f32x4 __attribute__((ext_vector_type(4)));

__device__ __forceinline__ float siluf(float x){ return x / (1.f + expf(-x)); }
__device__ __forceinline__ float sigmoidf(float x){ return 1.f / (1.f + expf(-x)); }
__device__ __forceinline__ float softplusf(float x){ return fmaxf(x, 0.f) + log1pf(expf(-fabsf(x))); }
__device__ __forceinline__ float geluf(float x){ return 0.5f * x * (1.f + erff(x * 0.70710678118654752f)); }
__device__ __forceinline__ short cvtbf(float f){
  unsigned u = __float_as_uint(f);
  u += 0x7FFF + ((u >> 16) & 1);
  return (short)(u >> 16);
}
__device__ __forceinline__ int perml(int l, int d){
  int h = l >> 4, w = l & 15;
  if (d & 1) w = 15 - w;
  if (d & 2) h = 15 - h;
  return (h << 4) | w;
}

// feat (B,C,H,W) -> x (B,L,C)
__global__ __launch_bounds__(256) void k_transpose(const float* __restrict__ feat, float* __restrict__ x){
  int idx = blockIdx.x * 256 + threadIdx.x;
  int c = idx & 255, l = (idx >> 8) & 255, b = idx >> 16;
  x[idx] = feat[((b * DD + c) * 16 + (l >> 4)) * 16 + (l & 15)];
}

__global__ __launch_bounds__(256) void k_gate(const float* __restrict__ alt_embed, const int* __restrict__ alt_idx,
                      const float* __restrict__ gate_w, const float* __restrict__ gate_b,
                      float* __restrict__ gate){
  int idx = blockIdx.x * 256 + threadIdx.x;
  int c = idx & 255, b = (idx >> 8) & 7, li = idx >> 11;
  const float* ae = alt_embed + alt_idx[b] * 32;
  const float* gw = gate_w + ((long)li * DD + c) * 32;
  float acc = gate_b[li * DD + c];
  #pragma unroll
  for (int j = 0; j < 32; j++) acc += ae[j] * gw[j];
  gate[idx] = sigmoidf(acc);
}

// Aexp[idx] = -exp(A_log[idx]), whole tensor (NL*ND*DIN*NS = 65536)
__global__ __launch_bounds__(256) void k_aexp(const float* __restrict__ A_log, float* __restrict__ Aexp){
  int idx = blockIdx.x * 256 + threadIdx.x;
  Aexp[idx] = -expf(A_log[idx]);
}

// seq[d,b,l,c] = x[b, perm_d(l), c]  (fp32 + bf16 copies)
__global__ __launch_bounds__(256) void k_seq(const float* __restrict__ x, float* __restrict__ seq,
                                             short* __restrict__ seq_bf){
  int idx = blockIdx.x * 256 + threadIdx.x;
  int c = idx & 255, l = (idx >> 8) & 255, b = (idx >> 16) & 7, d = idx >> 19;
  float v = x[((b * LL) + perml(l, d)) * DD + c];
  seq[idx] = v;
  seq_bf[idx] = cvtbf(v);
}

// MFMA bf16 GEMM: C[m,n] = act(sum_k A[m,k]*W[n,k] + bias[n])
template<int WM, int WN, int ACT, bool BIAS, bool OBF>
__global__ __launch_bounds__(256) void k_mgemm(const short* __restrict__ A, const float* __restrict__ W,
        const float* __restrict__ bias, void* __restrict__ Cv,
        int M, int N, int K, long aB, long wB, long cB){
  constexpr int TM = WM * 64, TN = WN * 64;
  __shared__ short As[TM][40];
  __shared__ short Ws[TN][40];
  int m0 = blockIdx.x * TM, n0 = blockIdx.y * TN, d = blockIdx.z;
  int t = threadIdx.x;
  int wave = t >> 6, lane = t & 63;
  int wr = wave / WN, wc = wave % WN;
  int lq = lane >> 4, lr = lane & 15;
  const short* Ad = A + (long)d * aB;
  const float* Wd = W + (long)d * wB;
  f32x4 acc[4][4];
  #pragma unroll
  for (int i = 0; i < 4; i++)
    #pragma unroll
    for (int j = 0; j < 4; j++) acc[i][j] = (f32x4){0.f, 0.f, 0.f, 0.f};

  constexpr int AREP = (TM * 32) / (256 * 8);
  constexpr int WREP = (TN * 32) / (256 * 4);

  for (int kb = 0; kb < K; kb += 32){
    #pragma unroll
    for (int r = 0; r < AREP; r++){
      int idx = r * 256 + t;
      int row = idx >> 2, c8 = idx & 3;
      s16x8 v = *(const s16x8*)(Ad + (long)(m0 + row) * K + kb + c8 * 8);
      *(s16x8*)&As[row][c8 * 8] = v;
    }
    #pragma unroll
    for (int r = 0; r < WREP; r++){
      int idx = r * 256 + t;
      int row = idx >> 3, c4 = idx & 7;
      int n = n0 + row;
      float4 v = {0.f, 0.f, 0.f, 0.f};
      if (n < N) v = *(const float4*)(Wd + (long)n * K + kb + c4 * 4);
      s16x4 sv = { cvtbf(v.x), cvtbf(v.y), cvtbf(v.z), cvtbf(v.w) };
      *(s16x4*)&Ws[row][c4 * 4] = sv;
    }
    __syncthreads();
    s16x8 af[4], wf[4];
    #pragma unroll
    for (int mi = 0; mi < 4; mi++) af[mi] = *(const s16x8*)&As[wr * 64 + mi * 16 + lr][lq * 8];
    #pragma unroll
    for (int ni = 0; ni < 4; ni++) wf[ni] = *(const s16x8*)&Ws[wc * 64 + ni * 16 + lr][lq * 8];
    #pragma unroll
    for (int mi = 0; mi < 4; mi++)
      #pragma unroll
      for (int ni = 0; ni < 4; ni++)
        acc[mi][ni] = __builtin_amdgcn_mfma_f32_16x16x32_bf16(af[mi], wf[ni], acc[mi][ni], 0, 0, 0);
    __syncthreads();
  }

  #pragma unroll
  for (int mi = 0; mi < 4; mi++){
    #pragma unroll
    for (int ni = 0; ni < 4; ni++){
      int n = n0 + wc * 64 + ni * 16 + lr;
      if (n < N){
        float bv = BIAS ? bias[n] : 0.f;
        #pragma unroll
        for (int r = 0; r < 4; r++){
          int m = m0 + wr * 64 + mi * 16 + lq * 4 + r;
          float v = acc[mi][ni][r] + bv;
          if (ACT == 1) v = geluf(v);
          if (OBF) ((short*)Cv)[(long)d * cB + (long)m * N + n] = cvtbf(v);
          else     ((float*)Cv)[(long)d * cB + (long)m * N + n] = v;
        }
      }
    }
  }
}

// causal depthwise conv (K=4) + silu; ch-major fp32 xct[db,i,l] AND row-major bf16 xcbf[db,l,i]
__global__ __launch_bounds__(256) void k_conv(const float* __restrict__ xz, const float* __restrict__ cw,
                      const float* __restrict__ cb, float* __restrict__ xct, short* __restrict__ xcbf){
  int it = blockIdx.x * 64, lc = blockIdx.y * 128, db = blockIdx.z;
  int d = db >> 3;
  int t = threadIdx.x;
  __shared__ float xs[64][131];
  const float* src = xz + (long)db * LL * 1024;
  for (int e = t; e < 131 * 64; e += 256){
    int il = e & 63, lh = e >> 6;
    int gl = lc - 3 + lh;
    xs[il][lh] = (gl >= 0) ? src[(long)gl * 1024 + it + il] : 0.f;
  }
  __syncthreads();
  const float* cwp = cw + ((long)d * DIN + it) * 4;
  const float* cbp = cb + (long)d * DIN + it;
  for (int e = t; e < 64 * 128; e += 256){
    int ll = e & 127, il = e >> 7;
    float acc = cbp[il];
    #pragma unroll
    for (int k = 0; k < 4; k++) acc += xs[il][ll + k] * cwp[il * 4 + k];
    xct[((long)db * DIN + it + il) * LL + lc + ll] = siluf(acc);
  }
  for (int e = t; e < 64 * 128; e += 256){
    int il = e & 63, lh = e >> 6;
    float acc = cbp[il];
    #pragma unroll
    for (int k = 0; k < 4; k++) acc += xs[il][lh + k] * cwp[il * 4 + k];
    xcbf[((long)db * LL + lc + lh) * DIN + it + il] = cvtbf(siluf(acc));
  }
}

// silu(z) transposed to channel-major zst[db,i,l]
__global__ __launch_bounds__(256) void k_zsilu(const float* __restrict__ xz, float* __restrict__ zst){
  int it = blockIdx.x * 64, lc = blockIdx.y * 128, db = blockIdx.z;
  int t = threadIdx.x;
  __shared__ float xs[64][129];
  const float* src = xz + (long)db * LL * 1024 + DIN;
  for (int e = t; e < 128 * 64; e += 256){
    int il = e & 63, lh = e >> 6;
    xs[il][lh] = src[(long)(lc + lh) * 1024 + it + il];
  }
  __syncthreads();
  for (int e = t; e < 64 * 128; e += 256){
    int ll = e & 127, il = e >> 7;
    zst[((long)db * DIN + it + il) * LL + lc + ll] = siluf(xs[il][ll]);
  }
}

// dt[db,i,l] = softplus(x_dbl[db,l,0:16] . dt_w[i,:] + dt_b[i]), channel-major out
__global__ __launch_bounds__(256) void k_dt(const float* __restrict__ x_dbl, const float* __restrict__ dt_w,
                     const float* __restrict__ dt_b, float* __restrict__ dtt){
  int it = blockIdx.x * 64, db = blockIdx.y;
  int d = db >> 3;
  int t = threadIdx.x;
  __shared__ float xs[256][17];
  __shared__ float wt[64][16];
  const float* xd = x_dbl + (long)db * LL * 48;
  for (int e = t; e < 256 * 16; e += 256){ int l = e >> 4, s = e & 15; xs[l][s] = xd[l * 48 + s]; }
  const float* wp = dt_w + ((long)d * DIN + it) * 16;
  for (int e = t; e < 64 * 16; e += 256){ wt[e >> 4][e & 15] = wp[e]; }
  __syncthreads();
  const float* bp = dt_b + (long)d * DIN + it;
  for (int r = 0; r < 64; r++){
    float acc = bp[r];
    #pragma unroll
    for (int s = 0; s < 16; s++) acc += xs[t][s] * wt[r][s];
    dtt[((long)db * DIN + it + r) * LL + t] = softplusf(acc);
  }
}

// windowed scan (K=8), restructured:
//  F[j][s] = dt[j]*xc[j]*Bp[j][s];  g[s] = F[l][s] + sum_{k=1..7} (prod E) * F[l-k][s]
//  y = (sum_s g[s]*Cp[s] + D*xc) * silu(z)
// LDS H: row j holds interleaved (E[j+1][s], F[j][s]) as 8 chunks of 4 words,
// chunk c stored at word offset j*32 + ((c ^ (j&7))<<2)  -> conflict-free b128.
__global__ __launch_bounds__(256) void k_scan(const float* __restrict__ dtt, const float* __restrict__ xct,
        const float* __restrict__ zst, const float* __restrict__ x_dbl,
        const float* __restrict__ Aexp, const float* __restrict__ Dp, float* __restrict__ yt){
  int i = blockIdx.x, b = blockIdx.y, d = blockIdx.z;
  int l = threadIdx.x;
  int db = d * BB + b;
  long base = ((long)db * DIN + i) * LL + l;
  __shared__ float H[256 * 32];   // 32 KB
  float dto = dtt[base];
  float xco = xct[base];
  const float* alp = Aexp + ((long)d * DIN + i) * NS;
  const float* xd = x_dbl + ((long)db * LL + l) * 48;
  float A[16], Bp[16], Cp[16];
  #pragma unroll
  for (int s4 = 0; s4 < 4; s4++){
    f32x4 av = *(const f32x4*)(alp + s4 * 4);
    f32x4 bv = *(const f32x4*)(xd + 16 + s4 * 4);
    f32x4 cv = *(const f32x4*)(xd + 32 + s4 * 4);
    #pragma unroll
    for (int r = 0; r < 4; r++){ A[s4*4+r] = av[r]; Bp[s4*4+r] = bv[r]; Cp[s4*4+r] = cv[r]; }
  }
  float dx = dto * xco;
  float E[16], F[16];
  #pragma unroll
  for (int s = 0; s < 16; s++){
    E[s] = expf(A[s] * dto);
    F[s] = dx * Bp[s];
  }
  // write E to row l-1, F to row l
  int rE = l - 1;
  #pragma unroll
  for (int s = 0; s < 16; s++){
    int c = s >> 1, w = (s & 1) * 2;
    if (l >= 1)   H[rE * 32 + (((c) ^ (rE & 7)) << 2) + w]     = E[s];
    if (l <= 254) H[l  * 32 + (((c) ^ (l  & 7)) << 2) + w + 1] = F[s];
  }
  __syncthreads();
  float dec[16], g[16];
  #pragma unroll
  for (int s = 0; s < 16; s++){ dec[s] = 1.f; g[s] = F[s]; }
  #pragma unroll
  for (int k = 1; k < 8; k++){
    int j = l - k;
    if (j >= 0){
      #pragma unroll
      for (int c = 0; c < 8; c++){
        f32x4 v = *(const f32x4*)&H[j * 32 + ((c ^ (j & 7)) << 2)];
        int s0 = c * 2;
        dec[s0]     *= v[0];  g[s0]     += dec[s0]     * v[1];
        dec[s0 + 1] *= v[2];  g[s0 + 1] += dec[s0 + 1] * v[3];
      }
    }
  }
  float acc = 0.f;
  #pragma unroll
  for (int s = 0; s < 16; s++) acc += g[s] * Cp[s];
  float y = (acc + Dp[(long)d * DIN + i] * xco) * zst[base];
  yt[base] = y;
}

// ch-major fp32 [db,i,l] -> row-major bf16 [db,l,i]
__global__ __launch_bounds__(256) void k_y2bf(const float* __restrict__ yt, short* __restrict__ ybf){
  __shared__ float tile[64][65];
  int i0 = blockIdx.x * 64, l0 = blockIdx.y * 64, db = blockIdx.z;
  int t = threadIdx.x;
  const float* src = yt + ((long)db * DIN + i0) * LL + l0;
  for (int e = t; e < 4096; e += 256){ int ii = e >> 6, ll = e & 63; tile[ii][ll] = src[(long)ii * LL + ll]; }
  __syncthreads();
  short* dst = ybf + ((long)db * LL + l0) * DIN + i0;
  for (int e = t; e < 4096; e += 256){ int ii = e & 63, ll = e >> 6; dst[(long)ll * DIN + ii] = cvtbf(tile[ii][ll]); }
}

// LN over C of (out_pre + residual), write unflipped bf16 into comb_bf[b, t, d*256+c]
__global__ __launch_bounds__(256) void k_ln1(const float* __restrict__ out_pre, const float* __restrict__ seq,
        const float* __restrict__ ng, const float* __restrict__ nb, short* __restrict__ comb_bf){
  int l = blockIdx.x, b = blockIdx.y, d = blockIdx.z, c = threadIdx.x;
  long row = ((long)(d * BB + b) * LL + l) * DD;
  float v = out_pre[row + c] + seq[row + c];
  float s = v, q = v * v;
  #pragma unroll
  for (int off = 32; off; off >>= 1){ s += __shfl_down(s, off); q += __shfl_down(q, off); }
  __shared__ float ps[4], pq[4], mv[2];
  int wid = c >> 6;
  if ((c & 63) == 0){ ps[wid] = s; pq[wid] = q; }
  __syncthreads();
  if (c == 0){
    float ts = ps[0] + ps[1] + ps[2] + ps[3];
    float tq = pq[0] + pq[1] + pq[2] + pq[3];
    float m = ts / 256.f;
    mv[0] = m; mv[1] = rsqrtf(tq / 256.f - m * m + 1e-5f);
  }
  __syncthreads();
  float o = (v - mv[0]) * mv[1] * ng[d * DD + c] + nb[d * DD + c];
  comb_bf[((long)b * LL + perml(l, d)) * 1024 + d * DD + c] = cvtbf(o);
}

// LN over C + gate multiply
__global__ __launch_bounds__(256) void k_ln2(const float* __restrict__ h2, const float* __restrict__ lg,
        const float* __restrict__ lb, const float* __restrict__ gate, float* __restrict__ dst){
  int l = blockIdx.x, b = blockIdx.y, c = threadIdx.x;
  long row = ((long)b * LL + l) * DD;
  float v = h2[row + c];
  float s = v, q = v * v;
  #pragma unroll
  for (int off = 32; off; off >>= 1){ s += __shfl_down(s, off); q += __shfl_down(q, off); }
  __shared__ float ps[4], pq[4], mv[2];
  int wid = c >> 6;
  if ((c & 63) == 0){ ps[wid] = s; pq[wid] = q; }
  __syncthreads();
  if (c == 0){
    float ts = ps[0] + ps[1] + ps[2] + ps[3];
    float tq = pq[0] + pq[1] + pq[2] + pq[3];
    float m = ts / 256.f;
    mv[0] = m; mv[1] = rsqrtf(tq / 256.f - m * m + 1e-5f);
  }
  __syncthreads();
  float o = (v - mv[0]) * mv[1] * lg[c] + lb[c];
  dst[row + c] = o * gate[b * DD + c];
}

extern "C" void kernel_launch(void* const* d_in, const int* in_sizes, int n_in,
                              void* d_out, int out_size, void* d_ws, size_t ws_size,
                              hipStream_t stream){
  const float* feat     = (const float*)d_in[0];
  const int*   alt_idx  = (const int*)d_in[1];
  const float* in_w     = (const float*)d_in[2];
  const float* dt_w     = (const float*)d_in[3];
  const float* dt_b     = (const float*)d_in[4];
  const float* A_log    = (const float*)d_in[5];
  const float* Dp       = (const float*)d_in[6];
  const float* xp_w     = (const float*)d_in[7];
  const float* conv_w   = (const float*)d_in[8];
  const float* conv_b   = (const float*)d_in[9];
  const float* out_w    = (const float*)d_in[10];
  const float* ng       = (const float*)d_in[11];
  const float* nb       = (const float*)d_in[12];
  const float* fw1      = (const float*)d_in[13];
  const float* fb1      = (const float*)d_in[14];
  const float* fw2      = (const float*)d_in[15];
  const float* fb2      = (const float*)d_in[16];
  const float* flg      = (const float*)d_in[17];
  const float* flb      = (const float*)d_in[18];
  const float* alt_embed= (const float*)d_in[19];
  const float* gate_w   = (const float*)d_in[20];
  const float* gate_b   = (const float*)d_in[21];
  float* out = (float*)d_out;

  float* p = (float*)d_ws;
  float* x_buf = p; p += (long)BL * DD;
  float* seq   = p; p += 4L * BL * DD;
  float* xz    = p; p += 4L * BL * 1024;
  float* xct   = p; p += 4L * BB * DIN * LL;
  float* zst   = p; p += 4L * BB * DIN * LL;
  float* xdbl  = p; p += 4L * BL * 48;
  float* dtt   = p; p += 4L * BB * DIN * LL;
  float* ytb   = p; p += 4L * BB * DIN * LL;
  float* opre  = p; p += 4L * BL * DD;
  float* h2    = p; p += (long)BL * DD;
  float* gateb = p; p += 2L * BB * DD;
  float* aexp  = p; p += (long)NL * NDIR * DIN * NS;
  short* sp = (short*)p;
  short* seq_bf  = sp; sp += 4L * BL * DD;
  short* xcbf    = sp; sp += 4L * BB * LL * DIN;
  short* ybf     = sp; sp += 4L * BB * LL * DIN;
  short* comb_bf = sp; sp += (long)BL * 1024;
  short* hfu_bf  = sp; sp += (long)BL * 512;

  k_transpose<<<2048, 256, 0, stream>>>(feat, x_buf);
  k_gate<<<16, 256, 0, stream>>>(alt_embed, alt_idx, gate_w, gate_b, gateb);
  k_aexp<<<256, 256, 0, stream>>>(A_log, aexp);

  for (int li = 0; li < NL; li++){
    k_seq<<<8192, 256, 0, stream>>>(x_buf, seq, seq_bf);
    // xz = seq @ in_w^T  (M=2048, N=1024, K=256, batch 4 dirs)
    k_mgemm<2, 2, 0, false, false><<<dim3(16, 8, 4), 256, 0, stream>>>(
        seq_bf, in_w + (long)li * NDIR * 1024 * 256, nullptr, xz,
        BL, 1024, 256, (long)BL * 256, 1024L * 256, (long)BL * 1024);
    k_conv<<<dim3(8, 2, 32), 256, 0, stream>>>(xz, conv_w + (long)li * NDIR * DIN * 4,
                                               conv_b + (long)li * NDIR * DIN, xct, xcbf);
    k_zsilu<<<dim3(8, 2, 32), 256, 0, stream>>>(xz, zst);
    // x_dbl = x_conv @ xp_w^T  (M=2048, N=48, K=512, batch 4)
    k_mgemm<4, 1, 0, false, false><<<dim3(8, 1, 4), 256, 0, stream>>>(
        xcbf, xp_w + (long)li * NDIR * 48 * 512, nullptr, xdbl,
        BL, 48, 512, (long)BB * LL * DIN, 48L * 512, (long)BL * 48);
    k_dt<<<dim3(8, 32), 256, 0, stream>>>(xdbl, dt_w + (long)li * NDIR * DIN * 16,
                                          dt_b + (long)li * NDIR * DIN, dtt);
    k_scan<<<dim3(512, 8, 4), 256, 0, stream>>>(dtt, xct, zst, xdbl,
        aexp + (long)li * NDIR * DIN * NS, Dp + (long)li * NDIR * DIN, ytb);
    k_y2bf<<<dim3(8, 4, 32), 256, 0, stream>>>(ytb, ybf);
    // out_pre = y @ out_w^T  (M=2048, N=256, K=512, batch 4)
    k_mgemm<2, 2, 0, false, false><<<dim3(16, 2, 4), 256, 0, stream>>>(
        ybf, out_w + (long)li * NDIR * 256 * 512, nullptr, opre,
        BL, 256, 512, (long)BB * LL * DIN, 256L * 512, (long)BL * 256);
    k_ln1<<<dim3(256, 8, 4), 256, 0, stream>>>(opre, seq, ng + (long)li * NDIR * DD,
                                               nb + (long)li * NDIR * DD, comb_bf);
    // hfu = gelu(comb @ fw1^T + fb1)  (M=2048, N=512, K=1024) -> bf16
    k_mgemm<2, 2, 1, true, true><<<dim3(16, 4, 1), 256, 0, stream>>>(
        comb_bf, fw1 + (long)li * 512 * 1024, fb1 + (long)li * 512, hfu_bf,
        BL, 512, 1024, 0, 0, 0);
    // h2 = hfu @ fw2^T + fb2  (M=2048, N=256, K=512)
    k_mgemm<2, 2, 0, true, false><<<dim3(16, 2, 1), 256, 0, stream>>>(
        hfu_bf, fw2 + (long)li * 256 * 512, fb2 + (long)li * 256, h2,
        BL, 256, 512, 0, 0, 0);
    float* dst = (li == NL - 1) ? out : x_buf;
    k_ln2<<<dim3(256, 8), 256, 0, stream>>>(h2, flg + (long)li * DD, flb + (long)li * DD,
                                            gateb + (long)li * BB * DD, dst);
  }
}

// Round 4
// 859.114 us; speedup vs baseline: 1.0409x; 1.0409x over previous
//
#include <hip/hip_runtime.h>
#include <math.h>

// Problem constants
#define NL 2
#define NDIR 4
#define DD 256     // D (channels)
#define DIN 512    // DI (inner)
#define NS 16      // N (state)
#define BB 8       // batch
#define LL 256     // L = H*W
#define BL 2048    // B*L

typedef short s16x8 __attribute__((ext_vector_type(8)));
typedef short s16x4 __attribute__((ext_vector_type(4)));
typedef float f32x4 __attribute__((ext_vector_type(4)));

__device__ __forceinline__ float siluf(float x){ return x / (1.f + expf(-x)); }
__device__ __forceinline__ float sigmoidf(float x){ return 1.f / (1.f + expf(-x)); }
__device__ __forceinline__ float softplusf(float x){ return fmaxf(x, 0.f) + log1pf(expf(-fabsf(x))); }
__device__ __forceinline__ float geluf(float x){ return 0.5f * x * (1.f + erff(x * 0.70710678118654752f)); }
__device__ __forceinline__ short cvtbf(float f){
  unsigned u = __float_as_uint(f);
  u += 0x7FFF + ((u >> 16) & 1);
  return (short)(u >> 16);
}
__device__ __forceinline__ int perml(int l, int d){
  int h = l >> 4, w = l & 15;
  if (d & 1) w = 15 - w;
  if (d & 2) h = 15 - h;
  return (h << 4) | w;
}

// feat (B,C,H,W) -> x (B,L,C)
__global__ __launch_bounds__(256) void k_transpose(const float* __restrict__ feat, float* __restrict__ x){
  int idx = blockIdx.x * 256 + threadIdx.x;
  int c = idx & 255, l = (idx >> 8) & 255, b = idx >> 16;
  x[idx] = feat[((b * DD + c) * 16 + (l >> 4)) * 16 + (l & 15)];
}

__global__ __launch_bounds__(256) void k_gate(const float* __restrict__ alt_embed, const int* __restrict__ alt_idx,
                      const float* __restrict__ gate_w, const float* __restrict__ gate_b,
                      float* __restrict__ gate){
  int idx = blockIdx.x * 256 + threadIdx.x;
  int c = idx & 255, b = (idx >> 8) & 7, li = idx >> 11;
  const float* ae = alt_embed + alt_idx[b] * 32;
  const float* gw = gate_w + ((long)li * DD + c) * 32;
  float acc = gate_b[li * DD + c];
  #pragma unroll
  for (int j = 0; j < 32; j++) acc += ae[j] * gw[j];
  gate[idx] = sigmoidf(acc);
}

// Aexp = -exp(A_log), whole tensor (65536)
__global__ __launch_bounds__(256) void k_aexp(const float* __restrict__ A_log, float* __restrict__ Aexp){
  int idx = blockIdx.x * 256 + threadIdx.x;
  Aexp[idx] = -expf(A_log[idx]);
}

// Convert all 5 GEMM weight tensors fp32->bf16 into one pool (4,653,056 elems, 4/thread)
#define WOFF_IN   0L
#define WOFF_XP   2097152L
#define WOFF_OUT  2293760L
#define WOFF_F1   3342336L
#define WOFF_F2   4390912L
#define WTOT      4653056L
__global__ __launch_bounds__(256) void k_wcvt(const float* __restrict__ s0, const float* __restrict__ s1,
      const float* __restrict__ s2, const float* __restrict__ s3, const float* __restrict__ s4,
      short* __restrict__ dst){
  long e = ((long)blockIdx.x * 256 + threadIdx.x) * 4;
  const float* src; long off;
  if      (e < WOFF_XP) { src = s0; off = e; }
  else if (e < WOFF_OUT){ src = s1; off = e - WOFF_XP; }
  else if (e < WOFF_F1) { src = s2; off = e - WOFF_OUT; }
  else if (e < WOFF_F2) { src = s3; off = e - WOFF_F1; }
  else                  { src = s4; off = e - WOFF_F2; }
  f32x4 v = *(const f32x4*)(src + off);
  s16x4 o = { cvtbf(v[0]), cvtbf(v[1]), cvtbf(v[2]), cvtbf(v[3]) };
  *(s16x4*)(dst + e) = o;
}

// MFMA bf16 GEMM: C[m,n] = act(sum_k A[m,k]*W[n,k] + bias[n])
// W: bf16 (N,K). ALAY 0: A bf16 row-major. ALAY 1: A fp32 gathered from x (B,L,C) via perml(dir=blockIdx.z).
template<int WM, int WN, int ACT, bool BIAS, bool OBF, int ALAY>
__global__ __launch_bounds__(256) void k_mgemm(const void* __restrict__ Av, const short* __restrict__ W,
        const float* __restrict__ bias, void* __restrict__ Cv,
        int M, int N, int K, long aB, long wB, long cB){
  constexpr int TM = WM * 64, TN = WN * 64;
  __shared__ short As[TM][40];
  __shared__ short Ws[TN][40];
  int m0 = blockIdx.x * TM, n0 = blockIdx.y * TN, d = blockIdx.z;
  int t = threadIdx.x;
  int wave = t >> 6, lane = t & 63;
  int wr = wave / WN, wc = wave % WN;
  int lq = lane >> 4, lr = lane & 15;
  const short* Wd = W + (long)d * wB;
  f32x4 acc[4][4];
  #pragma unroll
  for (int i = 0; i < 4; i++)
    #pragma unroll
    for (int j = 0; j < 4; j++) acc[i][j] = (f32x4){0.f, 0.f, 0.f, 0.f};

  for (int kb = 0; kb < K; kb += 32){
    if (ALAY == 0){
      const short* Ad = (const short*)Av + (long)d * aB;
      #pragma unroll
      for (int r = 0; r < WM; r++){           // TM*4 s16x8 units / 256 thr
        int e = r * 256 + t;
        int row = e >> 2, c8 = e & 3;
        s16x8 v = *(const s16x8*)(Ad + (long)(m0 + row) * K + kb + c8 * 8);
        *(s16x8*)&As[row][c8 * 8] = v;
      }
    } else {
      const float* Aq = (const float*)Av;     // x (B,L,C) fp32, gather rows by perml
      #pragma unroll
      for (int r = 0; r < 2 * WM; r++){       // TM*8 f32x4 units / 256 thr
        int e = r * 256 + t;
        int row = e >> 3, c4 = e & 7;
        int m = m0 + row;
        const float* src = Aq + ((long)((m >> 8) << 8) + perml(m & 255, d)) * 256 + kb + c4 * 4;
        f32x4 v = *(const f32x4*)src;
        s16x4 sv = { cvtbf(v[0]), cvtbf(v[1]), cvtbf(v[2]), cvtbf(v[3]) };
        *(s16x4*)&As[row][c4 * 4] = sv;
      }
    }
    #pragma unroll
    for (int r = 0; r < WN; r++){
      int e = r * 256 + t;
      int row = e >> 2, c8 = e & 3;
      int n = n0 + row;
      s16x8 v = (s16x8){0,0,0,0,0,0,0,0};
      if (n < N) v = *(const s16x8*)(Wd + (long)n * K + kb + c8 * 8);
      *(s16x8*)&Ws[row][c8 * 8] = v;
    }
    __syncthreads();
    s16x8 af[4], wf[4];
    #pragma unroll
    for (int mi = 0; mi < 4; mi++) af[mi] = *(const s16x8*)&As[wr * 64 + mi * 16 + lr][lq * 8];
    #pragma unroll
    for (int ni = 0; ni < 4; ni++) wf[ni] = *(const s16x8*)&Ws[wc * 64 + ni * 16 + lr][lq * 8];
    #pragma unroll
    for (int mi = 0; mi < 4; mi++)
      #pragma unroll
      for (int ni = 0; ni < 4; ni++)
        acc[mi][ni] = __builtin_amdgcn_mfma_f32_16x16x32_bf16(af[mi], wf[ni], acc[mi][ni], 0, 0, 0);
    __syncthreads();
  }

  #pragma unroll
  for (int mi = 0; mi < 4; mi++){
    #pragma unroll
    for (int ni = 0; ni < 4; ni++){
      int n = n0 + wc * 64 + ni * 16 + lr;
      if (n < N){
        float bv = BIAS ? bias[n] : 0.f;
        #pragma unroll
        for (int r = 0; r < 4; r++){
          int m = m0 + wr * 64 + mi * 16 + lq * 4 + r;
          float v = acc[mi][ni][r] + bv;
          if (ACT == 1) v = geluf(v);
          if (OBF) ((short*)Cv)[(long)d * cB + (long)m * N + n] = cvtbf(v);
          else     ((float*)Cv)[(long)d * cB + (long)m * N + n] = v;
        }
      }
    }
  }
}

// causal depthwise conv (K=4) + silu; ch-major fp32 xct[db,i,l] AND row-major bf16 xcbf[db,l,i]
__global__ __launch_bounds__(256) void k_conv(const float* __restrict__ xz, const float* __restrict__ cw,
                      const float* __restrict__ cb, float* __restrict__ xct, short* __restrict__ xcbf){
  int it = blockIdx.x * 64, lc = blockIdx.y * 128, db = blockIdx.z;
  int d = db >> 3;
  int t = threadIdx.x;
  __shared__ float xs[64][131];
  const float* src = xz + (long)db * LL * 1024;
  for (int e = t; e < 131 * 64; e += 256){
    int il = e & 63, lh = e >> 6;
    int gl = lc - 3 + lh;
    xs[il][lh] = (gl >= 0) ? src[(long)gl * 1024 + it + il] : 0.f;
  }
  __syncthreads();
  const float* cwp = cw + ((long)d * DIN + it) * 4;
  const float* cbp = cb + (long)d * DIN + it;
  for (int e = t; e < 64 * 128; e += 256){
    int ll = e & 127, il = e >> 7;
    float acc = cbp[il];
    #pragma unroll
    for (int k = 0; k < 4; k++) acc += xs[il][ll + k] * cwp[il * 4 + k];
    xct[((long)db * DIN + it + il) * LL + lc + ll] = siluf(acc);
  }
  for (int e = t; e < 64 * 128; e += 256){
    int il = e & 63, lh = e >> 6;
    float acc = cbp[il];
    #pragma unroll
    for (int k = 0; k < 4; k++) acc += xs[il][lh + k] * cwp[il * 4 + k];
    xcbf[((long)db * LL + lc + lh) * DIN + it + il] = cvtbf(siluf(acc));
  }
}

// silu(z) transposed to channel-major zst[db,i,l]
__global__ __launch_bounds__(256) void k_zsilu(const float* __restrict__ xz, float* __restrict__ zst){
  int it = blockIdx.x * 64, lc = blockIdx.y * 128, db = blockIdx.z;
  int t = threadIdx.x;
  __shared__ float xs[64][129];
  const float* src = xz + (long)db * LL * 1024 + DIN;
  for (int e = t; e < 128 * 64; e += 256){
    int il = e & 63, lh = e >> 6;
    xs[il][lh] = src[(long)(lc + lh) * 1024 + it + il];
  }
  __syncthreads();
  for (int e = t; e < 64 * 128; e += 256){
    int ll = e & 127, il = e >> 7;
    zst[((long)db * DIN + it + il) * LL + lc + ll] = siluf(xs[il][ll]);
  }
}

// windowed scan (K=8), T=2 l-per-thread, dt fused, conflict-free swizzled LDS.
// H row R (R = l+8, rows 0..7 are zero pad): 8 chunks of 4 words; chunk c at ((c^((R>>1)&7))<<2).
// chunks 0-3 = E[16], chunks 4-7 = F[16].
__global__ __launch_bounds__(128) void k_scan(const float* __restrict__ xct, const float* __restrict__ zst,
        const float* __restrict__ x_dbl, const float* __restrict__ Aexp,
        const float* __restrict__ dt_w, const float* __restrict__ dt_b,
        const float* __restrict__ Dp, float* __restrict__ yt){
  int i = blockIdx.x, b = blockIdx.y, d = blockIdx.z;
  int tl = threadIdx.x;          // 0..127
  int l0 = tl * 2;
  int db = d * BB + b;
  __shared__ float H[264 * 32];  // 33 KB
  // zero pad rows 0..7 (256 words)
  H[tl * 2] = 0.f; H[tl * 2 + 1] = 0.f;
  long base = ((long)db * DIN + i) * LL + l0;
  float2 xc2 = *(const float2*)&xct[base];
  float2 z2  = *(const float2*)&zst[base];
  const float* xd0 = x_dbl + ((long)db * LL + l0) * 48;
  const float* alp = Aexp + ((long)d * DIN + i) * NS;
  const float* wdt = dt_w + ((long)d * DIN + i) * 16;
  float bdt = dt_b[(long)d * DIN + i];

  float A[16], Bp0[16], Cp0[16], Bp1[16], Cp1[16];
  float dt0 = bdt, dt1 = bdt;
  #pragma unroll
  for (int s4 = 0; s4 < 4; s4++){
    f32x4 av = *(const f32x4*)(alp + s4 * 4);
    f32x4 w4 = *(const f32x4*)(wdt + s4 * 4);
    f32x4 d0 = *(const f32x4*)(xd0 + s4 * 4);
    f32x4 d1 = *(const f32x4*)(xd0 + 48 + s4 * 4);
    f32x4 b0 = *(const f32x4*)(xd0 + 16 + s4 * 4);
    f32x4 c0 = *(const f32x4*)(xd0 + 32 + s4 * 4);
    f32x4 b1 = *(const f32x4*)(xd0 + 64 + s4 * 4);
    f32x4 c1 = *(const f32x4*)(xd0 + 80 + s4 * 4);
    #pragma unroll
    for (int r = 0; r < 4; r++){
      int s = s4 * 4 + r;
      A[s] = av[r]; Bp0[s] = b0[r]; Cp0[s] = c0[r]; Bp1[s] = b1[r]; Cp1[s] = c1[r];
      dt0 += d0[r] * w4[r];
      dt1 += d1[r] * w4[r];
    }
  }
  dt0 = softplusf(dt0);
  dt1 = softplusf(dt1);
  float dx0 = dt0 * xc2.x, dx1 = dt1 * xc2.y;
  float E0[16], E1[16], F0[16], F1[16];
  #pragma unroll
  for (int s = 0; s < 16; s++){
    E0[s] = expf(A[s] * dt0);
    E1[s] = expf(A[s] * dt1);
    F0[s] = dx0 * Bp0[s];
    F1[s] = dx1 * Bp1[s];
  }
  // write rows R0 = l0+8, R1 = l0+9; (R0>>1)&7 == (R1>>1)&7 == (tl+4)&7
  {
    int xw = (tl + 4) & 7;
    float* r0p = H + (l0 + 8) * 32;
    float* r1p = H + (l0 + 9) * 32;
    #pragma unroll
    for (int c = 0; c < 4; c++){
      *(f32x4*)(r0p + ((c ^ xw) << 2))       = (f32x4){E0[c*4], E0[c*4+1], E0[c*4+2], E0[c*4+3]};
      *(f32x4*)(r0p + (((c + 4) ^ xw) << 2)) = (f32x4){F0[c*4], F0[c*4+1], F0[c*4+2], F0[c*4+3]};
      *(f32x4*)(r1p + ((c ^ xw) << 2))       = (f32x4){E1[c*4], E1[c*4+1], E1[c*4+2], E1[c*4+3]};
      *(f32x4*)(r1p + (((c + 4) ^ xw) << 2)) = (f32x4){F1[c*4], F1[c*4+1], F1[c*4+2], F1[c*4+3]};
    }
  }
  __syncthreads();
  float g0[16], g1[16], dec0[16], dec1[16];
  #pragma unroll
  for (int s = 0; s < 16; s++){
    g0[s] = F0[s];
    g1[s] = F1[s] + E1[s] * F0[s];
    dec0[s] = E0[s];
    dec1[s] = E1[s] * E0[s];
  }
  #pragma unroll
  for (int m = 1; m <= 6; m++){
    int R = l0 - m + 8;
    const float* rp = H + R * 32;
    int xr = (R >> 1) & 7;
    #pragma unroll
    for (int c = 0; c < 4; c++){
      f32x4 Ec = *(const f32x4*)(rp + ((c ^ xr) << 2));
      f32x4 Fc = *(const f32x4*)(rp + (((c + 4) ^ xr) << 2));
      #pragma unroll
      for (int r = 0; r < 4; r++){
        int s = c * 4 + r;
        g0[s] += dec0[s] * Fc[r];
        g1[s] += dec1[s] * Fc[r];
        dec0[s] *= Ec[r];
        dec1[s] *= Ec[r];
      }
    }
  }
  {
    int R = l0 - 7 + 8;
    const float* rp = H + R * 32;
    int xr = (R >> 1) & 7;
    #pragma unroll
    for (int c = 0; c < 4; c++){
      f32x4 Fc = *(const f32x4*)(rp + (((c + 4) ^ xr) << 2));
      #pragma unroll
      for (int r = 0; r < 4; r++) g0[c*4+r] += dec0[c*4+r] * Fc[r];
    }
  }
  float acc0 = 0.f, acc1 = 0.f;
  #pragma unroll
  for (int s = 0; s < 16; s++){ acc0 += g0[s] * Cp0[s]; acc1 += g1[s] * Cp1[s]; }
  float Di = Dp[(long)d * DIN + i];
  float2 y;
  y.x = (acc0 + Di * xc2.x) * z2.x;
  y.y = (acc1 + Di * xc2.y) * z2.y;
  *(float2*)&yt[base] = y;
}

// ch-major fp32 [db,i,l] -> row-major bf16 [db,l,i]
__global__ __launch_bounds__(256) void k_y2bf(const float* __restrict__ yt, short* __restrict__ ybf){
  __shared__ float tile[64][65];
  int i0 = blockIdx.x * 64, l0 = blockIdx.y * 64, db = blockIdx.z;
  int t = threadIdx.x;
  const float* src = yt + ((long)db * DIN + i0) * LL + l0;
  for (int e = t; e < 4096; e += 256){ int ii = e >> 6, ll = e & 63; tile[ii][ll] = src[(long)ii * LL + ll]; }
  __syncthreads();
  short* dst = ybf + ((long)db * LL + l0) * DIN + i0;
  for (int e = t; e < 4096; e += 256){ int ii = e & 63, ll = e >> 6; dst[(long)ll * DIN + ii] = cvtbf(tile[ii][ll]); }
}

// LN over C of (out_pre + residual from x via perml), write unflipped bf16 comb[b,t,d*256+c]
__global__ __launch_bounds__(256) void k_ln1(const float* __restrict__ out_pre, const float* __restrict__ x,
        const float* __restrict__ ng, const float* __restrict__ nb, short* __restrict__ comb_bf){
  int l = blockIdx.x, b = blockIdx.y, d = blockIdx.z, c = threadIdx.x;
  long row = ((long)(d * BB + b) * LL + l) * DD;
  int pl = perml(l, d);
  float v = out_pre[row + c] + x[((long)(b * LL) + pl) * DD + c];
  float s = v, q = v * v;
  #pragma unroll
  for (int off = 32; off; off >>= 1){ s += __shfl_down(s, off); q += __shfl_down(q, off); }
  __shared__ float ps[4], pq[4], mv[2];
  int wid = c >> 6;
  if ((c & 63) == 0){ ps[wid] = s; pq[wid] = q; }
  __syncthreads();
  if (c == 0){
    float ts = ps[0] + ps[1] + ps[2] + ps[3];
    float tq = pq[0] + pq[1] + pq[2] + pq[3];
    float m = ts / 256.f;
    mv[0] = m; mv[1] = rsqrtf(tq / 256.f - m * m + 1e-5f);
  }
  __syncthreads();
  float o = (v - mv[0]) * mv[1] * ng[d * DD + c] + nb[d * DD + c];
  comb_bf[((long)b * LL + pl) * 1024 + d * DD + c] = cvtbf(o);
}

// LN over C + gate multiply
__global__ __launch_bounds__(256) void k_ln2(const float* __restrict__ h2, const float* __restrict__ lg,
        const float* __restrict__ lb, const float* __restrict__ gate, float* __restrict__ dst){
  int l = blockIdx.x, b = blockIdx.y, c = threadIdx.x;
  long row = ((long)b * LL + l) * DD;
  float v = h2[row + c];
  float s = v, q = v * v;
  #pragma unroll
  for (int off = 32; off; off >>= 1){ s += __shfl_down(s, off); q += __shfl_down(q, off); }
  __shared__ float ps[4], pq[4], mv[2];
  int wid = c >> 6;
  if ((c & 63) == 0){ ps[wid] = s; pq[wid] = q; }
  __syncthreads();
  if (c == 0){
    float ts = ps[0] + ps[1] + ps[2] + ps[3];
    float tq = pq[0] + pq[1] + pq[2] + pq[3];
    float m = ts / 256.f;
    mv[0] = m; mv[1] = rsqrtf(tq / 256.f - m * m + 1e-5f);
  }
  __syncthreads();
  float o = (v - mv[0]) * mv[1] * lg[c] + lb[c];
  dst[row + c] = o * gate[b * DD + c];
}

extern "C" void kernel_launch(void* const* d_in, const int* in_sizes, int n_in,
                              void* d_out, int out_size, void* d_ws, size_t ws_size,
                              hipStream_t stream){
  const float* feat     = (const float*)d_in[0];
  const int*   alt_idx  = (const int*)d_in[1];
  const float* in_w     = (const float*)d_in[2];
  const float* dt_w     = (const float*)d_in[3];
  const float* dt_b     = (const float*)d_in[4];
  const float* A_log    = (const float*)d_in[5];
  const float* Dp       = (const float*)d_in[6];
  const float* xp_w     = (const float*)d_in[7];
  const float* conv_w   = (const float*)d_in[8];
  const float* conv_b   = (const float*)d_in[9];
  const float* out_w    = (const float*)d_in[10];
  const float* ng       = (const float*)d_in[11];
  const float* nb       = (const float*)d_in[12];
  const float* fw1      = (const float*)d_in[13];
  const float* fb1      = (const float*)d_in[14];
  const float* fw2      = (const float*)d_in[15];
  const float* fb2      = (const float*)d_in[16];
  const float* flg      = (const float*)d_in[17];
  const float* flb      = (const float*)d_in[18];
  const float* alt_embed= (const float*)d_in[19];
  const float* gate_w   = (const float*)d_in[20];
  const float* gate_b   = (const float*)d_in[21];
  float* out = (float*)d_out;

  float* p = (float*)d_ws;
  float* x_buf = p; p += (long)BL * DD;
  float* xz    = p; p += 4L * BL * 1024;
  float* xct   = p; p += 4L * BB * DIN * LL;
  float* zst   = p; p += 4L * BB * DIN * LL;
  float* xdbl  = p; p += 4L * BL * 48;
  float* ytb   = p; p += 4L * BB * DIN * LL;
  float* opre  = p; p += 4L * BL * DD;
  float* h2    = p; p += (long)BL * DD;
  float* gateb = p; p += 2L * BB * DD;
  float* aexp  = p; p += (long)NL * NDIR * DIN * NS;
  short* sp = (short*)p;
  short* wbf     = sp; sp += WTOT;
  short* xcbf    = sp; sp += 4L * BB * LL * DIN;
  short* ybf     = sp; sp += 4L * BB * LL * DIN;
  short* comb_bf = sp; sp += (long)BL * 1024;
  short* hfu_bf  = sp; sp += (long)BL * 512;

  k_transpose<<<2048, 256, 0, stream>>>(feat, x_buf);
  k_gate<<<16, 256, 0, stream>>>(alt_embed, alt_idx, gate_w, gate_b, gateb);
  k_aexp<<<256, 256, 0, stream>>>(A_log, aexp);
  k_wcvt<<<4544, 256, 0, stream>>>(in_w, xp_w, out_w, fw1, fw2, wbf);

  for (int li = 0; li < NL; li++){
    // xz = perm(x) @ in_w^T  (M=2048, N=1024, K=256, batch 4 dirs; A gathered from x_buf)
    k_mgemm<2, 2, 0, false, false, 1><<<dim3(16, 8, 4), 256, 0, stream>>>(
        x_buf, wbf + WOFF_IN + (long)li * NDIR * 1024 * 256, nullptr, xz,
        BL, 1024, 256, 0, 1024L * 256, (long)BL * 1024);
    k_conv<<<dim3(8, 2, 32), 256, 0, stream>>>(xz, conv_w + (long)li * NDIR * DIN * 4,
                                               conv_b + (long)li * NDIR * DIN, xct, xcbf);
    k_zsilu<<<dim3(8, 2, 32), 256, 0, stream>>>(xz, zst);
    // x_dbl = x_conv @ xp_w^T  (M=2048, N=48, K=512, batch 4)
    k_mgemm<4, 1, 0, false, false, 0><<<dim3(8, 1, 4), 256, 0, stream>>>(
        xcbf, wbf + WOFF_XP + (long)li * NDIR * 48 * 512, nullptr, xdbl,
        BL, 48, 512, (long)BB * LL * DIN, 48L * 512, (long)BL * 48);
    k_scan<<<dim3(512, 8, 4), 128, 0, stream>>>(xct, zst, xdbl,
        aexp + (long)li * NDIR * DIN * NS,
        dt_w + (long)li * NDIR * DIN * 16, dt_b + (long)li * NDIR * DIN,
        Dp + (long)li * NDIR * DIN, ytb);
    k_y2bf<<<dim3(8, 4, 32), 256, 0, stream>>>(ytb, ybf);
    // out_pre = y @ out_w^T  (M=2048, N=256, K=512, batch 4)
    k_mgemm<2, 2, 0, false, false, 0><<<dim3(16, 2, 4), 256, 0, stream>>>(
        ybf, wbf + WOFF_OUT + (long)li * NDIR * 256 * 512, nullptr, opre,
        BL, 256, 512, (long)BB * LL * DIN, 256L * 512, (long)BL * 256);
    k_ln1<<<dim3(256, 8, 4), 256, 0, stream>>>(opre, x_buf, ng + (long)li * NDIR * DD,
                                               nb + (long)li * NDIR * DD, comb_bf);
    // hfu = gelu(comb @ fw1^T + fb1)  (M=2048, N=512, K=1024) -> bf16
    k_mgemm<2, 2, 1, true, true, 0><<<dim3(16, 4, 1), 256, 0, stream>>>(
        comb_bf, wbf + WOFF_F1 + (long)li * 512 * 1024, fb1 + (long)li * 512, hfu_bf,
        BL, 512, 1024, 0, 0, 0);
    // h2 = hfu @ fw2^T + fb2  (M=2048, N=256, K=512)
    k_mgemm<2, 2, 0, true, false, 0><<<dim3(16, 2, 1), 256, 0, stream>>>(
        hfu_bf, wbf + WOFF_F2 + (long)li * 256 * 512, fb2 + (long)li * 256, h2,
        BL, 256, 512, 0, 0, 0);
    float* dst = (li == NL - 1) ? out : x_buf;
    k_ln2<<<dim3(256, 8), 256, 0, stream>>>(h2, flg + (long)li * DD, flb + (long)li * DD,
                                            gateb + (long)li * BB * DD, dst);
  }
}

// Round 5
// 620.028 us; speedup vs baseline: 1.4423x; 1.3856x over previous
//
#include <hip/hip_runtime.h>
#include <math.h>

// Problem constants
#define NL 2
#define NDIR 4
#define DD 256     // D (channels)
#define DIN 512    // DI (inner)
#define NS 16      // N (state)
#define BB 8       // batch
#define LL 256     // L = H*W
#define BL 2048    // B*L

typedef short s16x8 __attribute__((ext_vector_type(8)));
typedef short s16x4 __attribute__((ext_vector_type(4)));
typedef float f32x4 __attribute__((ext_vector_type(4)));

__device__ __forceinline__ float siluf(float x){ return x / (1.f + expf(-x)); }
__device__ __forceinline__ float sigmoidf(float x){ return 1.f / (1.f + expf(-x)); }
__device__ __forceinline__ float softplusf(float x){ return fmaxf(x, 0.f) + log1pf(expf(-fabsf(x))); }
__device__ __forceinline__ float geluf(float x){ return 0.5f * x * (1.f + erff(x * 0.70710678118654752f)); }
__device__ __forceinline__ short cvtbf(float f){
  unsigned u = __float_as_uint(f);
  u += 0x7FFF + ((u >> 16) & 1);
  return (short)(u >> 16);
}
__device__ __forceinline__ int perml(int l, int d){
  int h = l >> 4, w = l & 15;
  if (d & 1) w = 15 - w;
  if (d & 2) h = 15 - h;
  return (h << 4) | w;
}

// feat (B,C,H,W) -> x (B,L,C)
__global__ __launch_bounds__(256) void k_transpose(const float* __restrict__ feat, float* __restrict__ x){
  int idx = blockIdx.x * 256 + threadIdx.x;
  int c = idx & 255, l = (idx >> 8) & 255, b = idx >> 16;
  x[idx] = feat[((b * DD + c) * 16 + (l >> 4)) * 16 + (l & 15)];
}

__global__ __launch_bounds__(256) void k_gate(const float* __restrict__ alt_embed, const int* __restrict__ alt_idx,
                      const float* __restrict__ gate_w, const float* __restrict__ gate_b,
                      float* __restrict__ gate){
  int idx = blockIdx.x * 256 + threadIdx.x;
  int c = idx & 255, b = (idx >> 8) & 7, li = idx >> 11;
  const float* ae = alt_embed + alt_idx[b] * 32;
  const float* gw = gate_w + ((long)li * DD + c) * 32;
  float acc = gate_b[li * DD + c];
  #pragma unroll
  for (int j = 0; j < 32; j++) acc += ae[j] * gw[j];
  gate[idx] = sigmoidf(acc);
}

// Aexp = -exp(A_log), whole tensor (65536)
__global__ __launch_bounds__(256) void k_aexp(const float* __restrict__ A_log, float* __restrict__ Aexp){
  int idx = blockIdx.x * 256 + threadIdx.x;
  Aexp[idx] = -expf(A_log[idx]);
}

// Convert all 5 GEMM weight tensors fp32->bf16 into one pool
#define WOFF_IN   0L
#define WOFF_XP   2097152L
#define WOFF_OUT  2293760L
#define WOFF_F1   3342336L
#define WOFF_F2   4390912L
#define WTOT      4653056L
__global__ __launch_bounds__(256) void k_wcvt(const float* __restrict__ s0, const float* __restrict__ s1,
      const float* __restrict__ s2, const float* __restrict__ s3, const float* __restrict__ s4,
      short* __restrict__ dst){
  long e = ((long)blockIdx.x * 256 + threadIdx.x) * 4;
  const float* src; long off;
  if      (e < WOFF_XP) { src = s0; off = e; }
  else if (e < WOFF_OUT){ src = s1; off = e - WOFF_XP; }
  else if (e < WOFF_F1) { src = s2; off = e - WOFF_OUT; }
  else if (e < WOFF_F2) { src = s3; off = e - WOFF_F1; }
  else                  { src = s4; off = e - WOFF_F2; }
  f32x4 v = *(const f32x4*)(src + off);
  s16x4 o = { cvtbf(v[0]), cvtbf(v[1]), cvtbf(v[2]), cvtbf(v[3]) };
  *(s16x4*)(dst + e) = o;
}

// MFMA bf16 GEMM: C[m,n] = act(sum_k A[m,k]*W[n,k] + bias[n])
// W: bf16 (N,K). ALAY 0: A bf16 row-major. ALAY 1: A fp32 gathered from x (B,L,C) via perml(dir=blockIdx.z).
template<int WM, int WN, int ACT, bool BIAS, bool OBF, int ALAY>
__global__ __launch_bounds__(256) void k_mgemm(const void* __restrict__ Av, const short* __restrict__ W,
        const float* __restrict__ bias, void* __restrict__ Cv,
        int M, int N, int K, long aB, long wB, long cB){
  constexpr int TM = WM * 64, TN = WN * 64;
  __shared__ short As[TM][40];
  __shared__ short Ws[TN][40];
  int m0 = blockIdx.x * TM, n0 = blockIdx.y * TN, d = blockIdx.z;
  int t = threadIdx.x;
  int wave = t >> 6, lane = t & 63;
  int wr = wave / WN, wc = wave % WN;
  int lq = lane >> 4, lr = lane & 15;
  const short* Wd = W + (long)d * wB;
  f32x4 acc[4][4];
  #pragma unroll
  for (int i = 0; i < 4; i++)
    #pragma unroll
    for (int j = 0; j < 4; j++) acc[i][j] = (f32x4){0.f, 0.f, 0.f, 0.f};

  for (int kb = 0; kb < K; kb += 32){
    if (ALAY == 0){
      const short* Ad = (const short*)Av + (long)d * aB;
      #pragma unroll
      for (int r = 0; r < WM; r++){
        int e = r * 256 + t;
        int row = e >> 2, c8 = e & 3;
        s16x8 v = *(const s16x8*)(Ad + (long)(m0 + row) * K + kb + c8 * 8);
        *(s16x8*)&As[row][c8 * 8] = v;
      }
    } else {
      const float* Aq = (const float*)Av;
      #pragma unroll
      for (int r = 0; r < 2 * WM; r++){
        int e = r * 256 + t;
        int row = e >> 3, c4 = e & 7;
        int m = m0 + row;
        const float* src = Aq + ((long)((m >> 8) << 8) + perml(m & 255, d)) * 256 + kb + c4 * 4;
        f32x4 v = *(const f32x4*)src;
        s16x4 sv = { cvtbf(v[0]), cvtbf(v[1]), cvtbf(v[2]), cvtbf(v[3]) };
        *(s16x4*)&As[row][c4 * 4] = sv;
      }
    }
    #pragma unroll
    for (int r = 0; r < WN; r++){
      int e = r * 256 + t;
      int row = e >> 2, c8 = e & 3;
      int n = n0 + row;
      s16x8 v = (s16x8){0,0,0,0,0,0,0,0};
      if (n < N) v = *(const s16x8*)(Wd + (long)n * K + kb + c8 * 8);
      *(s16x8*)&Ws[row][c8 * 8] = v;
    }
    __syncthreads();
    s16x8 af[4], wf[4];
    #pragma unroll
    for (int mi = 0; mi < 4; mi++) af[mi] = *(const s16x8*)&As[wr * 64 + mi * 16 + lr][lq * 8];
    #pragma unroll
    for (int ni = 0; ni < 4; ni++) wf[ni] = *(const s16x8*)&Ws[wc * 64 + ni * 16 + lr][lq * 8];
    #pragma unroll
    for (int mi = 0; mi < 4; mi++)
      #pragma unroll
      for (int ni = 0; ni < 4; ni++)
        acc[mi][ni] = __builtin_amdgcn_mfma_f32_16x16x32_bf16(af[mi], wf[ni], acc[mi][ni], 0, 0, 0);
    __syncthreads();
  }

  #pragma unroll
  for (int mi = 0; mi < 4; mi++){
    #pragma unroll
    for (int ni = 0; ni < 4; ni++){
      int n = n0 + wc * 64 + ni * 16 + lr;
      if (n < N){
        float bv = BIAS ? bias[n] : 0.f;
        #pragma unroll
        for (int r = 0; r < 4; r++){
          int m = m0 + wr * 64 + mi * 16 + lq * 4 + r;
          float v = acc[mi][ni][r] + bv;
          if (ACT == 1) v = geluf(v);
          if (OBF) ((short*)Cv)[(long)d * cB + (long)m * N + n] = cvtbf(v);
          else     ((float*)Cv)[(long)d * cB + (long)m * N + n] = v;
        }
      }
    }
  }
}

// causal depthwise conv (K=4) + silu; row-major fp32 xcrow[db,l,i] + bf16 xcbf[db,l,i]
__global__ __launch_bounds__(256) void k_conv(const float* __restrict__ xz, const float* __restrict__ cw,
                      const float* __restrict__ cb, float* __restrict__ xcrow, short* __restrict__ xcbf){
  int it = blockIdx.x * 64, lc = blockIdx.y * 128, db = blockIdx.z;
  int d = db >> 3;
  int t = threadIdx.x;
  __shared__ float xs[64][131];
  const float* src = xz + (long)db * LL * 1024;
  for (int e = t; e < 131 * 64; e += 256){
    int il = e & 63, lh = e >> 6;
    int gl = lc - 3 + lh;
    xs[il][lh] = (gl >= 0) ? src[(long)gl * 1024 + it + il] : 0.f;
  }
  __syncthreads();
  const float* cwp = cw + ((long)d * DIN + it) * 4;
  const float* cbp = cb + (long)d * DIN + it;
  for (int e = t; e < 64 * 128; e += 256){
    int il = e & 63, lh = e >> 6;
    float acc = cbp[il];
    #pragma unroll
    for (int k = 0; k < 4; k++) acc += xs[il][lh + k] * cwp[il * 4 + k];
    float v = siluf(acc);
    long o = ((long)db * LL + lc + lh) * DIN + it + il;
    xcrow[o] = v;
    xcbf[o] = cvtbf(v);
  }
}

// zrow[db,l,i] = silu(xz[db,l,512+i])  — pure elementwise
__global__ __launch_bounds__(256) void k_zsilu(const float* __restrict__ xz, float* __restrict__ zrow){
  long idx = (long)blockIdx.x * 256 + threadIdx.x;   // 4*8*256*512 = 4,194,304
  int i = idx & 511;
  long rl = idx >> 9;                                 // db*256 + l
  zrow[idx] = siluf(xz[rl * 1024 + 512 + i]);
}

// dtrow[db,l,i] = softplus(x_dbl[db,l,0:16] . dt_w[d,i,:] + dt_b[d,i])
__global__ __launch_bounds__(512) void k_dt(const float* __restrict__ x_dbl, const float* __restrict__ dt_w,
     const float* __restrict__ dt_b, float* __restrict__ dtrow){
  int l = blockIdx.x, db = blockIdx.y;
  int d = db >> 3;
  int i = threadIdx.x;
  const float* xr = x_dbl + ((long)db * LL + l) * 48;
  const float* w = dt_w + ((long)d * DIN + i) * 16;
  float acc = dt_b[d * DIN + i];
  #pragma unroll
  for (int s4 = 0; s4 < 4; s4++){
    f32x4 xv = *(const f32x4*)(xr + s4 * 4);
    f32x4 wv = *(const f32x4*)(w + s4 * 4);
    #pragma unroll
    for (int r = 0; r < 4; r++) acc += xv[r] * wv[r];
  }
  dtrow[((long)db * LL + l) * DIN + i] = softplusf(acc);
}

// windowed scan (K=8) — chunked, LDS-free.
// Thread = (i, s-half) for one 8-l chunk [bs, bs+7].
// Within-chunk: h = E*h + F. Cross-chunk: Q[l]*T_r, T built by 7-step backward sweep,
// peeled by T -= R. s-halves combined via __shfl_xor(y,1). Writes ybf bf16 [db,l,i].
__global__ __launch_bounds__(512) void k_scan(
    const float* __restrict__ dtrow, const float* __restrict__ xcrow,
    const float* __restrict__ zrow, const float* __restrict__ x_dbl,
    const float* __restrict__ Aexp, const float* __restrict__ Dp,
    short* __restrict__ ybf){
  int bx = blockIdx.x;
  int itile = bx & 1, chunk = bx >> 1;
  int b = blockIdx.y, d = blockIdx.z;
  int db = d * BB + b;
  int tid = threadIdx.x;
  int half = tid & 1;
  int i = itile * 256 + (tid >> 1);
  int bs = chunk * 8;
  const float* alp = Aexp + ((long)(d * DIN + i)) * 16 + half * 8;
  float A[8];
  *(f32x4*)&A[0] = *(const f32x4*)(alp);
  *(f32x4*)&A[4] = *(const f32x4*)(alp + 4);
  float Di = Dp[d * DIN + i];
  const float* xdb = x_dbl + (long)db * LL * 48;
  long pix = (long)db * LL * DIN + i;   // + l*DIN

  float T[8], R[7][8], P[8];
  #pragma unroll
  for (int s = 0; s < 8; s++){ T[s] = 0.f; P[s] = 1.f; }
  if (bs > 0){
    #pragma unroll
    for (int m = 1; m <= 7; m++){
      int j = bs - m;
      float dt = dtrow[pix + (long)j * DIN];
      float xc = xcrow[pix + (long)j * DIN];
      float dx = dt * xc;
      const float* bp = xdb + j * 48 + 16 + half * 8;
      f32x4 b0 = *(const f32x4*)bp, b1 = *(const f32x4*)(bp + 4);
      #pragma unroll
      for (int s = 0; s < 8; s++){
        float Bv = (s < 4) ? b0[s] : b1[s - 4];
        float E = expf(A[s] * dt);
        float Rv = P[s] * (dx * Bv);
        R[m - 1][s] = Rv;
        T[s] += Rv;
        P[s] *= E;
      }
    }
  } else {
    #pragma unroll
    for (int m = 0; m < 7; m++)
      #pragma unroll
      for (int s = 0; s < 8; s++) R[m][s] = 0.f;
  }
  float h[8], Q[8];
  #pragma unroll
  for (int s = 0; s < 8; s++){ h[s] = 0.f; Q[s] = 1.f; }
  #pragma unroll
  for (int r = 0; r < 8; r++){
    int l = bs + r;
    float dt = dtrow[pix + (long)l * DIN];
    float xc = xcrow[pix + (long)l * DIN];
    float z  = zrow [pix + (long)l * DIN];
    float dx = dt * xc;
    const float* bp = xdb + l * 48 + 16 + half * 8;
    const float* cp = xdb + l * 48 + 32 + half * 8;
    f32x4 b0 = *(const f32x4*)bp, b1 = *(const f32x4*)(bp + 4);
    f32x4 c0 = *(const f32x4*)cp, c1 = *(const f32x4*)(cp + 4);
    float y = 0.f;
    #pragma unroll
    for (int s = 0; s < 8; s++){
      float Bv = (s < 4) ? b0[s] : b1[s - 4];
      float Cv = (s < 4) ? c0[s] : c1[s - 4];
      float E = expf(A[s] * dt);
      h[s] = E * h[s] + dx * Bv;
      Q[s] *= E;
      y += Cv * (h[s] + Q[s] * T[s]);
    }
    y += __shfl_xor(y, 1);
    if (half == 0){
      float outv = (y + Di * xc) * z;
      ybf[pix + (long)l * DIN] = cvtbf(outv);
    }
    if (r < 7){
      #pragma unroll
      for (int s = 0; s < 8; s++) T[s] -= R[6 - r][s];
    }
  }
}

// LN over C of (out_pre + residual from x via perml), write unflipped bf16 comb[b,t,d*256+c]
__global__ __launch_bounds__(256) void k_ln1(const float* __restrict__ out_pre, const float* __restrict__ x,
        const float* __restrict__ ng, const float* __restrict__ nb, short* __restrict__ comb_bf){
  int l = blockIdx.x, b = blockIdx.y, d = blockIdx.z, c = threadIdx.x;
  long row = ((long)(d * BB + b) * LL + l) * DD;
  int pl = perml(l, d);
  float v = out_pre[row + c] + x[((long)(b * LL) + pl) * DD + c];
  float s = v, q = v * v;
  #pragma unroll
  for (int off = 32; off; off >>= 1){ s += __shfl_down(s, off); q += __shfl_down(q, off); }
  __shared__ float ps[4], pq[4], mv[2];
  int wid = c >> 6;
  if ((c & 63) == 0){ ps[wid] = s; pq[wid] = q; }
  __syncthreads();
  if (c == 0){
    float ts = ps[0] + ps[1] + ps[2] + ps[3];
    float tq = pq[0] + pq[1] + pq[2] + pq[3];
    float m = ts / 256.f;
    mv[0] = m; mv[1] = rsqrtf(tq / 256.f - m * m + 1e-5f);
  }
  __syncthreads();
  float o = (v - mv[0]) * mv[1] * ng[d * DD + c] + nb[d * DD + c];
  comb_bf[((long)b * LL + pl) * 1024 + d * DD + c] = cvtbf(o);
}

// LN over C + gate multiply
__global__ __launch_bounds__(256) void k_ln2(const float* __restrict__ h2, const float* __restrict__ lg,
        const float* __restrict__ lb, const float* __restrict__ gate, float* __restrict__ dst){
  int l = blockIdx.x, b = blockIdx.y, c = threadIdx.x;
  long row = ((long)b * LL + l) * DD;
  float v = h2[row + c];
  float s = v, q = v * v;
  #pragma unroll
  for (int off = 32; off; off >>= 1){ s += __shfl_down(s, off); q += __shfl_down(q, off); }
  __shared__ float ps[4], pq[4], mv[2];
  int wid = c >> 6;
  if ((c & 63) == 0){ ps[wid] = s; pq[wid] = q; }
  __syncthreads();
  if (c == 0){
    float ts = ps[0] + ps[1] + ps[2] + ps[3];
    float tq = pq[0] + pq[1] + pq[2] + pq[3];
    float m = ts / 256.f;
    mv[0] = m; mv[1] = rsqrtf(tq / 256.f - m * m + 1e-5f);
  }
  __syncthreads();
  float o = (v - mv[0]) * mv[1] * lg[c] + lb[c];
  dst[row + c] = o * gate[b * DD + c];
}

extern "C" void kernel_launch(void* const* d_in, const int* in_sizes, int n_in,
                              void* d_out, int out_size, void* d_ws, size_t ws_size,
                              hipStream_t stream){
  const float* feat     = (const float*)d_in[0];
  const int*   alt_idx  = (const int*)d_in[1];
  const float* in_w     = (const float*)d_in[2];
  const float* dt_w     = (const float*)d_in[3];
  const float* dt_b     = (const float*)d_in[4];
  const float* A_log    = (const float*)d_in[5];
  const float* Dp       = (const float*)d_in[6];
  const float* xp_w     = (const float*)d_in[7];
  const float* conv_w   = (const float*)d_in[8];
  const float* conv_b   = (const float*)d_in[9];
  const float* out_w    = (const float*)d_in[10];
  const float* ng       = (const float*)d_in[11];
  const float* nb       = (const float*)d_in[12];
  const float* fw1      = (const float*)d_in[13];
  const float* fb1      = (const float*)d_in[14];
  const float* fw2      = (const float*)d_in[15];
  const float* fb2      = (const float*)d_in[16];
  const float* flg      = (const float*)d_in[17];
  const float* flb      = (const float*)d_in[18];
  const float* alt_embed= (const float*)d_in[19];
  const float* gate_w   = (const float*)d_in[20];
  const float* gate_b   = (const float*)d_in[21];
  float* out = (float*)d_out;

  float* p = (float*)d_ws;
  float* x_buf = p; p += (long)BL * DD;
  float* xz    = p; p += 4L * BL * 1024;
  float* xcrow = p; p += 4L * BB * LL * DIN;
  float* zrow  = p; p += 4L * BB * LL * DIN;
  float* xdbl  = p; p += 4L * BL * 48;
  float* dtrow = p; p += 4L * BB * LL * DIN;
  float* opre  = p; p += 4L * BL * DD;
  float* h2    = p; p += (long)BL * DD;
  float* gateb = p; p += 2L * BB * DD;
  float* aexp  = p; p += (long)NL * NDIR * DIN * NS;
  short* sp = (short*)p;
  short* wbf     = sp; sp += WTOT;
  short* xcbf    = sp; sp += 4L * BB * LL * DIN;
  short* ybf     = sp; sp += 4L * BB * LL * DIN;
  short* comb_bf = sp; sp += (long)BL * 1024;
  short* hfu_bf  = sp; sp += (long)BL * 512;

  k_transpose<<<2048, 256, 0, stream>>>(feat, x_buf);
  k_gate<<<16, 256, 0, stream>>>(alt_embed, alt_idx, gate_w, gate_b, gateb);
  k_aexp<<<256, 256, 0, stream>>>(A_log, aexp);
  k_wcvt<<<4544, 256, 0, stream>>>(in_w, xp_w, out_w, fw1, fw2, wbf);

  for (int li = 0; li < NL; li++){
    // xz = perm(x) @ in_w^T  (M=2048, N=1024, K=256, batch 4 dirs; A gathered from x_buf)
    k_mgemm<2, 2, 0, false, false, 1><<<dim3(16, 8, 4), 256, 0, stream>>>(
        x_buf, wbf + WOFF_IN + (long)li * NDIR * 1024 * 256, nullptr, xz,
        BL, 1024, 256, 0, 1024L * 256, (long)BL * 1024);
    k_conv<<<dim3(8, 2, 32), 256, 0, stream>>>(xz, conv_w + (long)li * NDIR * DIN * 4,
                                               conv_b + (long)li * NDIR * DIN, xcrow, xcbf);
    k_zsilu<<<16384, 256, 0, stream>>>(xz, zrow);
    // x_dbl = x_conv @ xp_w^T  (M=2048, N=48, K=512, batch 4)
    k_mgemm<4, 1, 0, false, false, 0><<<dim3(8, 1, 4), 256, 0, stream>>>(
        xcbf, wbf + WOFF_XP + (long)li * NDIR * 48 * 512, nullptr, xdbl,
        BL, 48, 512, (long)BB * LL * DIN, 48L * 512, (long)BL * 48);
    k_dt<<<dim3(256, 32), 512, 0, stream>>>(xdbl, dt_w + (long)li * NDIR * DIN * 16,
                                            dt_b + (long)li * NDIR * DIN, dtrow);
    k_scan<<<dim3(64, 8, 4), 512, 0, stream>>>(dtrow, xcrow, zrow, xdbl,
        aexp + (long)li * NDIR * DIN * NS, Dp + (long)li * NDIR * DIN, ybf);
    // out_pre = y @ out_w^T  (M=2048, N=256, K=512, batch 4)
    k_mgemm<2, 2, 0, false, false, 0><<<dim3(16, 2, 4), 256, 0, stream>>>(
        ybf, wbf + WOFF_OUT + (long)li * NDIR * 256 * 512, nullptr, opre,
        BL, 256, 512, (long)BB * LL * DIN, 256L * 512, (long)BL * 256);
    k_ln1<<<dim3(256, 8, 4), 256, 0, stream>>>(opre, x_buf, ng + (long)li * NDIR * DD,
                                               nb + (long)li * NDIR * DD, comb_bf);
    // hfu = gelu(comb @ fw1^T + fb1)  (M=2048, N=512, K=1024) -> bf16
    k_mgemm<2, 2, 1, true, true, 0><<<dim3(16, 4, 1), 256, 0, stream>>>(
        comb_bf, wbf + WOFF_F1 + (long)li * 512 * 1024, fb1 + (long)li * 512, hfu_bf,
        BL, 512, 1024, 0, 0, 0);
    // h2 = hfu @ fw2^T + fb2  (M=2048, N=256, K=512)
    k_mgemm<2, 2, 0, true, false, 0><<<dim3(16, 2, 1), 256, 0, stream>>>(
        hfu_bf, wbf + WOFF_F2 + (long)li * 256 * 512, fb2 + (long)li * 256, h2,
        BL, 256, 512, 0, 0, 0);
    float* dst = (li == NL - 1) ? out : x_buf;
    k_ln2<<<dim3(256, 8), 256, 0, stream>>>(h2, flg + (long)li * DD, flb + (long)li * DD,
                                            gateb + (long)li * BB * DD, dst);
  }
}

// Round 6
// 560.243 us; speedup vs baseline: 1.5962x; 1.1067x over previous
//
#include <hip/hip_runtime.h>
#include <math.h>

// Problem constants
#define NL 2
#define NDIR 4
#define DD 256     // D (channels)
#define DIN 512    // DI (inner)
#define NS 16      // N (state)
#define BB 8       // batch
#define LL 256     // L = H*W
#define BL 2048    // B*L

typedef short s16x8 __attribute__((ext_vector_type(8)));
typedef short s16x4 __attribute__((ext_vector_type(4)));
typedef float f32x4 __attribute__((ext_vector_type(4)));

// fast-math device helpers (tolerance 4.56e-2 >> 2-ulp native error)
__device__ __forceinline__ float fsilu(float x){ return __fdividef(x, 1.f + __expf(-x)); }
__device__ __forceinline__ float fsigmoid(float x){ return __fdividef(1.f, 1.f + __expf(-x)); }
__device__ __forceinline__ float fsoftplus(float x){ return fmaxf(x, 0.f) + __logf(1.f + __expf(-fabsf(x))); }
__device__ __forceinline__ float geluf(float x){ return 0.5f * x * (1.f + erff(x * 0.70710678118654752f)); }
__device__ __forceinline__ short cvtbf(float f){
  unsigned u = __float_as_uint(f);
  u += 0x7FFF + ((u >> 16) & 1);
  return (short)(u >> 16);
}
__device__ __forceinline__ int perml(int l, int d){
  int h = l >> 4, w = l & 15;
  if (d & 1) w = 15 - w;
  if (d & 2) h = 15 - h;
  return (h << 4) | w;
}

// feat (B,C,H,W) -> x (B,L,C)
__global__ __launch_bounds__(256) void k_transpose(const float* __restrict__ feat, float* __restrict__ x){
  int idx = blockIdx.x * 256 + threadIdx.x;
  int c = idx & 255, l = (idx >> 8) & 255, b = idx >> 16;
  x[idx] = feat[((b * DD + c) * 16 + (l >> 4)) * 16 + (l & 15)];
}

__global__ __launch_bounds__(256) void k_gate(const float* __restrict__ alt_embed, const int* __restrict__ alt_idx,
                      const float* __restrict__ gate_w, const float* __restrict__ gate_b,
                      float* __restrict__ gate){
  int idx = blockIdx.x * 256 + threadIdx.x;
  int c = idx & 255, b = (idx >> 8) & 7, li = idx >> 11;
  const float* ae = alt_embed + alt_idx[b] * 32;
  const float* gw = gate_w + ((long)li * DD + c) * 32;
  float acc = gate_b[li * DD + c];
  #pragma unroll
  for (int j = 0; j < 32; j++) acc += ae[j] * gw[j];
  gate[idx] = fsigmoid(acc);
}

// Aexp = -exp(A_log), whole tensor (65536); keep libm exp (once per call, accuracy anchor)
__global__ __launch_bounds__(256) void k_aexp(const float* __restrict__ A_log, float* __restrict__ Aexp){
  int idx = blockIdx.x * 256 + threadIdx.x;
  Aexp[idx] = -expf(A_log[idx]);
}

// Convert all 5 GEMM weight tensors fp32->bf16 into one pool
#define WOFF_IN   0L
#define WOFF_XP   2097152L
#define WOFF_OUT  2293760L
#define WOFF_F1   3342336L
#define WOFF_F2   4390912L
#define WTOT      4653056L
__global__ __launch_bounds__(256) void k_wcvt(const float* __restrict__ s0, const float* __restrict__ s1,
      const float* __restrict__ s2, const float* __restrict__ s3, const float* __restrict__ s4,
      short* __restrict__ dst){
  long e = ((long)blockIdx.x * 256 + threadIdx.x) * 4;
  const float* src; long off;
  if      (e < WOFF_XP) { src = s0; off = e; }
  else if (e < WOFF_OUT){ src = s1; off = e - WOFF_XP; }
  else if (e < WOFF_F1) { src = s2; off = e - WOFF_OUT; }
  else if (e < WOFF_F2) { src = s3; off = e - WOFF_F1; }
  else                  { src = s4; off = e - WOFF_F2; }
  f32x4 v = *(const f32x4*)(src + off);
  s16x4 o = { cvtbf(v[0]), cvtbf(v[1]), cvtbf(v[2]), cvtbf(v[3]) };
  *(s16x4*)(dst + e) = o;
}

// MFMA bf16 GEMM: C[m,n] = act(sum_k A[m,k]*W[n,k] + bias[n])
// W: bf16 (N,K). ALAY 0: A bf16 row-major. ALAY 1: A fp32 gathered from x (B,L,C) via perml(dir=blockIdx.z).
// ACT: 0 none, 1 gelu, 2 split-silu (n<512 raw->Cv, n>=512 silu->Cv2; both row stride 512)
template<int WM, int WN, int ACT, bool BIAS, bool OBF, int ALAY>
__global__ __launch_bounds__(256) void k_mgemm(const void* __restrict__ Av, const short* __restrict__ W,
        const float* __restrict__ bias, void* __restrict__ Cv, void* __restrict__ Cv2,
        int M, int N, int K, long aB, long wB, long cB){
  constexpr int TM = WM * 64, TN = WN * 64;
  __shared__ short As[TM][40];
  __shared__ short Ws[TN][40];
  int m0 = blockIdx.x * TM, n0 = blockIdx.y * TN, d = blockIdx.z;
  int t = threadIdx.x;
  int wave = t >> 6, lane = t & 63;
  int wr = wave / WN, wc = wave % WN;
  int lq = lane >> 4, lr = lane & 15;
  const short* Wd = W + (long)d * wB;
  f32x4 acc[4][4];
  #pragma unroll
  for (int i = 0; i < 4; i++)
    #pragma unroll
    for (int j = 0; j < 4; j++) acc[i][j] = (f32x4){0.f, 0.f, 0.f, 0.f};

  for (int kb = 0; kb < K; kb += 32){
    if (ALAY == 0){
      const short* Ad = (const short*)Av + (long)d * aB;
      #pragma unroll
      for (int r = 0; r < WM; r++){
        int e = r * 256 + t;
        int row = e >> 2, c8 = e & 3;
        s16x8 v = *(const s16x8*)(Ad + (long)(m0 + row) * K + kb + c8 * 8);
        *(s16x8*)&As[row][c8 * 8] = v;
      }
    } else {
      const float* Aq = (const float*)Av;
      #pragma unroll
      for (int r = 0; r < 2 * WM; r++){
        int e = r * 256 + t;
        int row = e >> 3, c4 = e & 7;
        int m = m0 + row;
        const float* src = Aq + ((long)((m >> 8) << 8) + perml(m & 255, d)) * 256 + kb + c4 * 4;
        f32x4 v = *(const f32x4*)src;
        s16x4 sv = { cvtbf(v[0]), cvtbf(v[1]), cvtbf(v[2]), cvtbf(v[3]) };
        *(s16x4*)&As[row][c4 * 4] = sv;
      }
    }
    #pragma unroll
    for (int r = 0; r < WN; r++){
      int e = r * 256 + t;
      int row = e >> 2, c8 = e & 3;
      int n = n0 + row;
      s16x8 v = (s16x8){0,0,0,0,0,0,0,0};
      if (n < N) v = *(const s16x8*)(Wd + (long)n * K + kb + c8 * 8);
      *(s16x8*)&Ws[row][c8 * 8] = v;
    }
    __syncthreads();
    s16x8 af[4], wf[4];
    #pragma unroll
    for (int mi = 0; mi < 4; mi++) af[mi] = *(const s16x8*)&As[wr * 64 + mi * 16 + lr][lq * 8];
    #pragma unroll
    for (int ni = 0; ni < 4; ni++) wf[ni] = *(const s16x8*)&Ws[wc * 64 + ni * 16 + lr][lq * 8];
    #pragma unroll
    for (int mi = 0; mi < 4; mi++)
      #pragma unroll
      for (int ni = 0; ni < 4; ni++)
        acc[mi][ni] = __builtin_amdgcn_mfma_f32_16x16x32_bf16(af[mi], wf[ni], acc[mi][ni], 0, 0, 0);
    __syncthreads();
  }

  #pragma unroll
  for (int mi = 0; mi < 4; mi++){
    #pragma unroll
    for (int ni = 0; ni < 4; ni++){
      int n = n0 + wc * 64 + ni * 16 + lr;
      if (n < N){
        float bv = BIAS ? bias[n] : 0.f;
        #pragma unroll
        for (int r = 0; r < 4; r++){
          int m = m0 + wr * 64 + mi * 16 + lq * 4 + r;
          float v = acc[mi][ni][r] + bv;
          if (ACT == 1) v = geluf(v);
          if (ACT == 2){
            if (n < DIN) ((float*)Cv )[(long)d * cB + (long)m * DIN + n]         = v;
            else         ((float*)Cv2)[(long)d * cB + (long)m * DIN + (n - DIN)] = fsilu(v);
          } else {
            if (OBF) ((short*)Cv)[(long)d * cB + (long)m * N + n] = cvtbf(v);
            else     ((float*)Cv)[(long)d * cB + (long)m * N + n] = v;
          }
        }
      }
    }
  }
}

// causal depthwise conv (K=4) + silu on xinb[db,l,512]; row-major fp32 xcrow + bf16 xcbf
__global__ __launch_bounds__(256) void k_conv(const float* __restrict__ xinb, const float* __restrict__ cw,
                      const float* __restrict__ cb, float* __restrict__ xcrow, short* __restrict__ xcbf){
  int it = blockIdx.x * 64, lc = blockIdx.y * 128, db = blockIdx.z;
  int d = db >> 3;
  int t = threadIdx.x;
  __shared__ float xs[64][131];
  const float* src = xinb + (long)db * LL * DIN;
  for (int e = t; e < 131 * 64; e += 256){
    int il = e & 63, lh = e >> 6;
    int gl = lc - 3 + lh;
    xs[il][lh] = (gl >= 0) ? src[(long)gl * DIN + it + il] : 0.f;
  }
  __syncthreads();
  const float* cwp = cw + ((long)d * DIN + it) * 4;
  const float* cbp = cb + (long)d * DIN + it;
  for (int e = t; e < 64 * 128; e += 256){
    int il = e & 63, lh = e >> 6;
    float acc = cbp[il];
    #pragma unroll
    for (int k = 0; k < 4; k++) acc += xs[il][lh + k] * cwp[il * 4 + k];
    float v = fsilu(acc);
    long o = ((long)db * LL + lc + lh) * DIN + it + il;
    xcrow[o] = v;
    xcbf[o] = cvtbf(v);
  }
}

// dtrow[db,l,i] = softplus(x_dbl[db,l,0:16] . dt_w[d,i,:] + dt_b[d,i])
__global__ __launch_bounds__(512) void k_dt(const float* __restrict__ x_dbl, const float* __restrict__ dt_w,
     const float* __restrict__ dt_b, float* __restrict__ dtrow){
  int l = blockIdx.x, db = blockIdx.y;
  int d = db >> 3;
  int i = threadIdx.x;
  const float* xr = x_dbl + ((long)db * LL + l) * 48;
  const float* w = dt_w + ((long)d * DIN + i) * 16;
  float acc = dt_b[d * DIN + i];
  #pragma unroll
  for (int s4 = 0; s4 < 4; s4++){
    f32x4 xv = *(const f32x4*)(xr + s4 * 4);
    f32x4 wv = *(const f32x4*)(w + s4 * 4);
    #pragma unroll
    for (int r = 0; r < 4; r++) acc += xv[r] * wv[r];
  }
  dtrow[((long)db * LL + l) * DIN + i] = fsoftplus(acc);
}

// windowed scan (K=8) — chunked, LDS-free, native exp.
__global__ __launch_bounds__(512) void k_scan(
    const float* __restrict__ dtrow, const float* __restrict__ xcrow,
    const float* __restrict__ zrow, const float* __restrict__ x_dbl,
    const float* __restrict__ Aexp, const float* __restrict__ Dp,
    short* __restrict__ ybf){
  int bx = blockIdx.x;
  int itile = bx & 1, chunk = bx >> 1;
  int b = blockIdx.y, d = blockIdx.z;
  int db = d * BB + b;
  int tid = threadIdx.x;
  int half = tid & 1;
  int i = itile * 256 + (tid >> 1);
  int bs = chunk * 8;
  const float* alp = Aexp + ((long)(d * DIN + i)) * 16 + half * 8;
  float A[8];
  *(f32x4*)&A[0] = *(const f32x4*)(alp);
  *(f32x4*)&A[4] = *(const f32x4*)(alp + 4);
  float Di = Dp[d * DIN + i];
  const float* xdb = x_dbl + (long)db * LL * 48;
  long pix = (long)db * LL * DIN + i;   // + l*DIN

  float T[8], R[7][8], P[8];
  #pragma unroll
  for (int s = 0; s < 8; s++){ T[s] = 0.f; P[s] = 1.f; }
  if (bs > 0){
    #pragma unroll
    for (int m = 1; m <= 7; m++){
      int j = bs - m;
      float dt = dtrow[pix + (long)j * DIN];
      float xc = xcrow[pix + (long)j * DIN];
      float dx = dt * xc;
      const float* bp = xdb + j * 48 + 16 + half * 8;
      f32x4 b0 = *(const f32x4*)bp, b1 = *(const f32x4*)(bp + 4);
      #pragma unroll
      for (int s = 0; s < 8; s++){
        float Bv = (s < 4) ? b0[s] : b1[s - 4];
        float E = __expf(A[s] * dt);
        float Rv = P[s] * (dx * Bv);
        R[m - 1][s] = Rv;
        T[s] += Rv;
        P[s] *= E;
      }
    }
  } else {
    #pragma unroll
    for (int m = 0; m < 7; m++)
      #pragma unroll
      for (int s = 0; s < 8; s++) R[m][s] = 0.f;
  }
  float h[8], Q[8];
  #pragma unroll
  for (int s = 0; s < 8; s++){ h[s] = 0.f; Q[s] = 1.f; }
  #pragma unroll
  for (int r = 0; r < 8; r++){
    int l = bs + r;
    float dt = dtrow[pix + (long)l * DIN];
    float xc = xcrow[pix + (long)l * DIN];
    float z  = zrow [pix + (long)l * DIN];
    float dx = dt * xc;
    const float* bp = xdb + l * 48 + 16 + half * 8;
    const float* cp = xdb + l * 48 + 32 + half * 8;
    f32x4 b0 = *(const f32x4*)bp, b1 = *(const f32x4*)(bp + 4);
    f32x4 c0 = *(const f32x4*)cp, c1 = *(const f32x4*)(cp + 4);
    float y = 0.f;
    #pragma unroll
    for (int s = 0; s < 8; s++){
      float Bv = (s < 4) ? b0[s] : b1[s - 4];
      float Cv = (s < 4) ? c0[s] : c1[s - 4];
      float E = __expf(A[s] * dt);
      h[s] = E * h[s] + dx * Bv;
      Q[s] *= E;
      y += Cv * (h[s] + Q[s] * T[s]);
    }
    y += __shfl_xor(y, 1);
    if (half == 0){
      float outv = (y + Di * xc) * z;
      ybf[pix + (long)l * DIN] = cvtbf(outv);
    }
    if (r < 7){
      #pragma unroll
      for (int s = 0; s < 8; s++) T[s] -= R[6 - r][s];
    }
  }
}

// LN over C of (out_pre + residual from x via perml), write unflipped bf16 comb[b,t,d*256+c]
__global__ __launch_bounds__(256) void k_ln1(const float* __restrict__ out_pre, const float* __restrict__ x,
        const float* __restrict__ ng, const float* __restrict__ nb, short* __restrict__ comb_bf){
  int l = blockIdx.x, b = blockIdx.y, d = blockIdx.z, c = threadIdx.x;
  long row = ((long)(d * BB + b) * LL + l) * DD;
  int pl = perml(l, d);
  float v = out_pre[row + c] + x[((long)(b * LL) + pl) * DD + c];
  float s = v, q = v * v;
  #pragma unroll
  for (int off = 32; off; off >>= 1){ s += __shfl_down(s, off); q += __shfl_down(q, off); }
  __shared__ float ps[4], pq[4], mv[2];
  int wid = c >> 6;
  if ((c & 63) == 0){ ps[wid] = s; pq[wid] = q; }
  __syncthreads();
  if (c == 0){
    float ts = ps[0] + ps[1] + ps[2] + ps[3];
    float tq = pq[0] + pq[1] + pq[2] + pq[3];
    float m = ts / 256.f;
    mv[0] = m; mv[1] = rsqrtf(tq / 256.f - m * m + 1e-5f);
  }
  __syncthreads();
  float o = (v - mv[0]) * mv[1] * ng[d * DD + c] + nb[d * DD + c];
  comb_bf[((long)b * LL + pl) * 1024 + d * DD + c] = cvtbf(o);
}

// LN over C + gate multiply
__global__ __launch_bounds__(256) void k_ln2(const float* __restrict__ h2, const float* __restrict__ lg,
        const float* __restrict__ lb, const float* __restrict__ gate, float* __restrict__ dst){
  int l = blockIdx.x, b = blockIdx.y, c = threadIdx.x;
  long row = ((long)b * LL + l) * DD;
  float v = h2[row + c];
  float s = v, q = v * v;
  #pragma unroll
  for (int off = 32; off; off >>= 1){ s += __shfl_down(s, off); q += __shfl_down(q, off); }
  __shared__ float ps[4], pq[4], mv[2];
  int wid = c >> 6;
  if ((c & 63) == 0){ ps[wid] = s; pq[wid] = q; }
  __syncthreads();
  if (c == 0){
    float ts = ps[0] + ps[1] + ps[2] + ps[3];
    float tq = pq[0] + pq[1] + pq[2] + pq[3];
    float m = ts / 256.f;
    mv[0] = m; mv[1] = rsqrtf(tq / 256.f - m * m + 1e-5f);
  }
  __syncthreads();
  float o = (v - mv[0]) * mv[1] * lg[c] + lb[c];
  dst[row + c] = o * gate[b * DD + c];
}

extern "C" void kernel_launch(void* const* d_in, const int* in_sizes, int n_in,
                              void* d_out, int out_size, void* d_ws, size_t ws_size,
                              hipStream_t stream){
  const float* feat     = (const float*)d_in[0];
  const int*   alt_idx  = (const int*)d_in[1];
  const float* in_w     = (const float*)d_in[2];
  const float* dt_w     = (const float*)d_in[3];
  const float* dt_b     = (const float*)d_in[4];
  const float* A_log    = (const float*)d_in[5];
  const float* Dp       = (const float*)d_in[6];
  const float* xp_w     = (const float*)d_in[7];
  const float* conv_w   = (const float*)d_in[8];
  const float* conv_b   = (const float*)d_in[9];
  const float* out_w    = (const float*)d_in[10];
  const float* ng       = (const float*)d_in[11];
  const float* nb       = (const float*)d_in[12];
  const float* fw1      = (const float*)d_in[13];
  const float* fb1      = (const float*)d_in[14];
  const float* fw2      = (const float*)d_in[15];
  const float* fb2      = (const float*)d_in[16];
  const float* flg      = (const float*)d_in[17];
  const float* flb      = (const float*)d_in[18];
  const float* alt_embed= (const float*)d_in[19];
  const float* gate_w   = (const float*)d_in[20];
  const float* gate_b   = (const float*)d_in[21];
  float* out = (float*)d_out;

  float* p = (float*)d_ws;
  float* x_buf = p; p += (long)BL * DD;
  float* xinb  = p; p += 4L * BL * DIN;
  float* zrow  = p; p += 4L * BL * DIN;
  float* xcrow = p; p += 4L * BL * DIN;
  float* xdbl  = p; p += 4L * BL * 48;
  float* dtrow = p; p += 4L * BL * DIN;
  float* opre  = p; p += 4L * BL * DD;
  float* h2    = p; p += (long)BL * DD;
  float* gateb = p; p += 2L * BB * DD;
  float* aexp  = p; p += (long)NL * NDIR * DIN * NS;
  short* sp = (short*)p;
  short* wbf     = sp; sp += WTOT;
  short* xcbf    = sp; sp += 4L * BL * DIN;
  short* ybf     = sp; sp += 4L * BL * DIN;
  short* comb_bf = sp; sp += (long)BL * 1024;
  short* hfu_bf  = sp; sp += (long)BL * 512;

  k_transpose<<<2048, 256, 0, stream>>>(feat, x_buf);
  k_gate<<<16, 256, 0, stream>>>(alt_embed, alt_idx, gate_w, gate_b, gateb);
  k_aexp<<<256, 256, 0, stream>>>(A_log, aexp);
  k_wcvt<<<4544, 256, 0, stream>>>(in_w, xp_w, out_w, fw1, fw2, wbf);

  for (int li = 0; li < NL; li++){
    // xz = perm(x) @ in_w^T  (M=2048, N=1024, K=256, batch 4 dirs; split epilogue: x_in raw, z silu)
    k_mgemm<2, 2, 2, false, false, 1><<<dim3(16, 8, 4), 256, 0, stream>>>(
        x_buf, wbf + WOFF_IN + (long)li * NDIR * 1024 * 256, nullptr, xinb, zrow,
        BL, 1024, 256, 0, 1024L * 256, (long)BL * DIN);
    k_conv<<<dim3(8, 2, 32), 256, 0, stream>>>(xinb, conv_w + (long)li * NDIR * DIN * 4,
                                               conv_b + (long)li * NDIR * DIN, xcrow, xcbf);
    // x_dbl = x_conv @ xp_w^T  (M=2048, N=48, K=512, batch 4)
    k_mgemm<4, 1, 0, false, false, 0><<<dim3(8, 1, 4), 256, 0, stream>>>(
        xcbf, wbf + WOFF_XP + (long)li * NDIR * 48 * 512, nullptr, xdbl, nullptr,
        BL, 48, 512, (long)BL * DIN, 48L * 512, (long)BL * 48);
    k_dt<<<dim3(256, 32), 512, 0, stream>>>(xdbl, dt_w + (long)li * NDIR * DIN * 16,
                                            dt_b + (long)li * NDIR * DIN, dtrow);
    k_scan<<<dim3(64, 8, 4), 512, 0, stream>>>(dtrow, xcrow, zrow, xdbl,
        aexp + (long)li * NDIR * DIN * NS, Dp + (long)li * NDIR * DIN, ybf);
    // out_pre = y @ out_w^T  (M=2048, N=256, K=512, batch 4)
    k_mgemm<2, 2, 0, false, false, 0><<<dim3(16, 2, 4), 256, 0, stream>>>(
        ybf, wbf + WOFF_OUT + (long)li * NDIR * 256 * 512, nullptr, opre, nullptr,
        BL, 256, 512, (long)BL * DIN, 256L * 512, (long)BL * 256);
    k_ln1<<<dim3(256, 8, 4), 256, 0, stream>>>(opre, x_buf, ng + (long)li * NDIR * DD,
                                               nb + (long)li * NDIR * DD, comb_bf);
    // hfu = gelu(comb @ fw1^T + fb1)  (M=2048, N=512, K=1024) -> bf16
    k_mgemm<2, 2, 1, true, true, 0><<<dim3(16, 4, 1), 256, 0, stream>>>(
        comb_bf, wbf + WOFF_F1 + (long)li * 512 * 1024, fb1 + (long)li * 512, hfu_bf, nullptr,
        BL, 512, 1024, 0, 0, 0);
    // h2 = hfu @ fw2^T + fb2  (M=2048, N=256, K=512)
    k_mgemm<2, 2, 0, true, false, 0><<<dim3(16, 2, 1), 256, 0, stream>>>(
        hfu_bf, wbf + WOFF_F2 + (long)li * 256 * 512, fb2 + (long)li * 256, h2, nullptr,
        BL, 256, 512, 0, 0, 0);
    float* dst = (li == NL - 1) ? out : x_buf;
    k_ln2<<<dim3(256, 8), 256, 0, stream>>>(h2, flg + (long)li * DD, flb + (long)li * DD,
                                            gateb + (long)li * BB * DD, dst);
  }
}